// Round 12
// baseline (177.082 us; speedup 1.0000x reference)
//
#include <hip/hip_runtime.h>
#include <stdint.h>

// Problem constants (reference: B=4, S=2048, D=512, H=8, d_head=64)
#define NB  4
#define SS  2048
#define DD  512
#define HH  8
#define DHH 64
#define MM  (NB * SS)   // 8192 rows

typedef __attribute__((ext_vector_type(8))) short bf16x8;  // 8 bf16 in 4 VGPRs
typedef __attribute__((ext_vector_type(4))) float f32x4;   // MFMA C/D frag
typedef __attribute__((ext_vector_type(4))) short s16x4;   // 8 B pack

union fu32 { float f; unsigned u; };
union pfu  { uint4 u; bf16x8 v; };

// fp32 -> bf16 round-to-nearest-even (bit pattern in a short)
static __device__ __forceinline__ short f2bf(float f) {
  fu32 a; a.f = f;
  unsigned u = a.u;
  return (short)((u + 0x7fffu + ((u >> 16) & 1u)) >> 16);
}
static __device__ __forceinline__ float bf2f(short s) {
  fu32 t; t.u = ((unsigned)(unsigned short)s) << 16;
  return t.f;
}

// async global->LDS, 16 B/lane; LDS dest = wave-uniform base + lane*16
static __device__ __forceinline__ void async16(const void* g, void* l) {
  __builtin_amdgcn_global_load_lds(
      (__attribute__((address_space(1))) unsigned*)(void*)g,
      (__attribute__((address_space(3))) unsigned*)l, 16, 0, 0);
}

// ------------------------------- prep: x->bf16 (blocks 0..2047) and
//                                 W[k][n] fp32 -> Wt[n][k] bf16 (2048..2303)
__global__ __launch_bounds__(256) void prep_kernel(
    const float* __restrict__ x, short* __restrict__ xb,
    const float* __restrict__ W0, const float* __restrict__ W1,
    const float* __restrict__ W2, const float* __restrict__ W3,
    short* __restrict__ T0, short* __restrict__ T1,
    short* __restrict__ T2, short* __restrict__ T3) {
  const int bid = blockIdx.x, tid = threadIdx.x;
  if (bid < 2048) {
    int i = (bid * 256 + tid) * 8;
    float4 v0 = *(const float4*)(x + i);
    float4 v1 = *(const float4*)(x + i + 4);
    bf16x8 o;
    o[0] = f2bf(v0.x); o[1] = f2bf(v0.y); o[2] = f2bf(v0.z); o[3] = f2bf(v0.w);
    o[4] = f2bf(v1.x); o[5] = f2bf(v1.y); o[6] = f2bf(v1.z); o[7] = f2bf(v1.w);
    *(bf16x8*)(xb + i) = o;
  } else {
    int z = bid - 2048;                 // 0..255
    int widx = z >> 6, rem = z & 63;
    const float* W = widx == 0 ? W0 : widx == 1 ? W1 : widx == 2 ? W2 : W3;
    short*       T = widx == 0 ? T0 : widx == 1 ? T1 : widx == 2 ? T2 : T3;
    int n  = (rem & 7) * 64 + (tid & 63);
    int k0 = (rem >> 3) * 64 + (tid >> 6) * 16;
    bf16x8 t0, t1;
#pragma unroll
    for (int j = 0; j < 8; ++j) t0[j] = f2bf(W[(size_t)(k0 + j) * DD + n]);
#pragma unroll
    for (int j = 0; j < 8; ++j) t1[j] = f2bf(W[(size_t)(k0 + 8 + j) * DD + n]);
    *(bf16x8*)(T + (size_t)n * DD + k0)     = t0;
    *(bf16x8*)(T + (size_t)n * DD + k0 + 8) = t1;
  }
}

// ---------------------------------------- fused QKV GEMM: 64x128, N = 1536
// grid (12,128) = 1536 blocks -> 4+ blocks/CU.  global_load_lds staging,
// XOR-swizzled segments.  Epilogue: q,k -> [B,H,S,64] (q pre-scaled),
// v -> [B,H,64,S] bf16.
__global__ __launch_bounds__(256, 4) void gemm_qkv_kernel(
    const short* __restrict__ A, const short* __restrict__ Bt,
    const float* __restrict__ bq, const float* __restrict__ bk,
    const float* __restrict__ bv, short* __restrict__ qout,
    short* __restrict__ kout, short* __restrict__ vtout, float qscale) {
  __shared__ __align__(16) short a_sh[64 * 64];
  __shared__ __align__(16) short b_sh[128 * 64];
  const int tid  = threadIdx.x;
  const int w    = tid >> 6, lane = tid & 63, quad = lane >> 4, l16 = lane & 15;
  const int m0   = blockIdx.y * 64, n0 = blockIdx.x * 128;
  const int mw   = (w >> 1) * 32,   nw = (w & 1) * 64;
  const int rw   = lane >> 3, seg = lane & 7, gs = seg ^ rw;  // row&7 == rw
  const int sxz  = l16 & 7;   // fragment-read swizzle key

  f32x4 acc[2][4];
#pragma unroll
  for (int i = 0; i < 2; ++i)
#pragma unroll
    for (int j = 0; j < 4; ++j) acc[i][j] = {0.f, 0.f, 0.f, 0.f};

  for (int kt = 0; kt < DD; kt += 64) {
    __syncthreads();
    {
      const short* ga = A  + (size_t)(m0 + w * 16 + rw) * DD + kt + gs * 8;
      const short* gb = Bt + (size_t)(n0 + w * 32 + rw) * DD + kt + gs * 8;
#pragma unroll
      for (int i = 0; i < 2; ++i)
        async16(ga + (size_t)i * 8 * DD, &a_sh[(w * 16 + i * 8) * 64]);
#pragma unroll
      for (int i = 0; i < 4; ++i)
        async16(gb + (size_t)i * 8 * DD, &b_sh[(w * 32 + i * 8) * 64]);
    }
    __syncthreads();
#pragma unroll
    for (int ks = 0; ks < 2; ++ks) {
      const int so = ((ks * 4 + quad) ^ sxz) * 8;
      bf16x8 af[2], bfr[4];
#pragma unroll
      for (int mt = 0; mt < 2; ++mt)
        af[mt] = *(const bf16x8*)&a_sh[(mw + mt * 16 + l16) * 64 + so];
#pragma unroll
      for (int nt = 0; nt < 4; ++nt)
        bfr[nt] = *(const bf16x8*)&b_sh[(nw + nt * 16 + l16) * 64 + so];
#pragma unroll
      for (int mt = 0; mt < 2; ++mt)
#pragma unroll
        for (int nt = 0; nt < 4; ++nt)
          acc[mt][nt] = __builtin_amdgcn_mfma_f32_16x16x32_bf16(
              af[mt], bfr[nt], acc[mt][nt], 0, 0, 0);
    }
  }

#pragma unroll
  for (int nt = 0; nt < 4; ++nt) {
    const int n   = n0 + nw + nt * 16 + l16;   // 0..1535
    const int sg  = n >> 9, n9 = n & 511, h = n9 >> 6, d = n & 63;
    const float bval = (sg == 0 ? bq : sg == 1 ? bk : bv)[n9];
    const float scl  = (sg == 0) ? qscale : 1.0f;
#pragma unroll
    for (int mt = 0; mt < 2; ++mt) {
      const int mb = m0 + mw + mt * 16 + quad * 4;   // C row = quad*4 + r
      const int bi = mb >> 11, s = mb & (SS - 1);
      if (sg == 2) {
        s16x4 pk;
#pragma unroll
        for (int r = 0; r < 4; ++r) pk[r] = f2bf(acc[mt][nt][r] + bval);
        *(s16x4*)&vtout[((size_t)(bi * HH + h) * DHH + d) * SS + s] = pk;
      } else {
        short* o = (sg == 0) ? qout : kout;
        const size_t base = ((size_t)(bi * HH + h) * SS + s) * DHH + d;
#pragma unroll
        for (int r = 0; r < 4; ++r)
          o[base + (size_t)r * DHH] = f2bf((acc[mt][nt][r] + bval) * scl);
      }
    }
  }
}

// ----------------------------------------------- flash attention, key-split
// qt=4 register blocking: 64 queries/wave, 256/block -> each kf/vf
// ds_read_b128 feeds 4 MFMAs (DS-pipe traffic per unit work halves) and the
// wave has 4 independent dependency chains.  S^T = K·Q^T; P fragments
// assembled in registers (pack -> ^16 exchange -> select -> 4 ds_bpermute);
// softmax denominator via MFMA-vs-ones; zero-shuffle normalization.
__global__ __launch_bounds__(256, 2) void attn_kernel(
    const short* __restrict__ Qa, const short* __restrict__ Ka,
    const short* __restrict__ Vt, short* __restrict__ Op0,
    short* __restrict__ Op1, float* __restrict__ lpw) {
  __shared__ __align__(16) short k_sh[128 * 64];     // K tile, swizzled segs
  __shared__ __align__(16) short vt_sh[64 * 128];    // V^T tile, swizzled segs

  const int tid  = threadIdx.x;
  const int w    = tid >> 6, lane = tid & 63, quad = lane >> 4, l16 = lane & 15;
  // XCD-aware decode: xcd = n&7; 8 (b,h,half) groups x 8 q-tiles per XCD
  const int n    = blockIdx.x;                 // 0..511
  const int grp  = (n & 7) * 8 + ((n >> 3) & 7);   // (b,h,half) group, 0..63
  const int qt_b = n >> 6;                     // 0..7 (256-query tiles)
  const int half = grp & 1, h = (grp >> 1) & 7, b = grp >> 4;
  const int q0   = qt_b * 256;
  const int rw = lane >> 3, seg = lane & 7, gs = seg ^ rw;
  const int sxz = l16 & 7;
  const size_t base = (size_t)(b * HH + h) * SS * DHH;
  const short* Qg = Qa + base + (size_t)(q0 + w * 64) * DHH;
  const short* Kg = Ka + base;
  const short* Vg = Vt + base;           // [64][S]

  // Q fragments (usable as A or B operand: same lane map)
  bf16x8 qf[4][2];
#pragma unroll
  for (int qt = 0; qt < 4; ++qt)
#pragma unroll
    for (int ks = 0; ks < 2; ++ks)
      qf[qt][ks] = *(const bf16x8*)(Qg + (size_t)(qt * 16 + l16) * DHH + ks * 32 + quad * 8);

  bf16x8 ones;
#pragma unroll
  for (int j = 0; j < 8; ++j) ones[j] = (short)0x3F80;   // bf16 1.0

  f32x4 o_acc[4][4];
#pragma unroll
  for (int qt = 0; qt < 4; ++qt)
#pragma unroll
    for (int dt = 0; dt < 4; ++dt) o_acc[qt][dt] = {0.f, 0.f, 0.f, 0.f};
  f32x4 l_acc[4];
#pragma unroll
  for (int qt = 0; qt < 4; ++qt) l_acc[qt] = {0.f, 0.f, 0.f, 0.f};

  // bpermute byte-addresses for the verified cross-quad gather:
  // dwords 0/1 pull from src_quad = (quad&1)*2 + (quad>>1); dwords 2/3 from ^1
  const int addrA = ((((quad & 1) << 1) + (quad >> 1)) * 16 + l16) * 4;
  const int addrB = addrA ^ 64;
  const bool qeven = (quad & 1) == 0;

  const int kstart = half * (SS / 2);

  for (int kb = kstart; kb < kstart + SS / 2; kb += 128) {
    __syncthreads();   // WAR on k_sh / vt_sh
    {
      const short* gk = Kg + (size_t)(kb + w * 32 + rw) * DHH + gs * 8;
#pragma unroll
      for (int i = 0; i < 4; ++i)
        async16(gk + (size_t)i * 8 * DHH, &k_sh[(w * 32 + i * 8) * 64]);
#pragma unroll
      for (int i = 0; i < 4; ++i) {
        const int d = w * 16 + i * 4 + (lane >> 4);
        const int gseg = (lane & 15) ^ (d & 15);
        async16(Vg + (size_t)d * SS + kb + gseg * 8,
                &vt_sh[(w * 16 + i * 4) * 128]);
      }
    }
    __syncthreads();

    // 4 chunks of 32 keys: QK^T (2 tiles) -> exp2/pack -> permute -> PV + l
#pragma unroll
    for (int ck = 0; ck < 4; ++ck) {
      uint2 pk[4][2];   // [qt][tile]
#pragma unroll
      for (int t = 0; t < 2; ++t) {
        const int knt = ck * 2 + t;
        bf16x8 kf0 = *(const bf16x8*)&k_sh[(knt * 16 + l16) * 64 + ((0 * 4 + quad) ^ sxz) * 8];
        bf16x8 kf1 = *(const bf16x8*)&k_sh[(knt * 16 + l16) * 64 + ((1 * 4 + quad) ^ sxz) * 8];
#pragma unroll
        for (int qt = 0; qt < 4; ++qt) {
          f32x4 s = {0.f, 0.f, 0.f, 0.f};
          s = __builtin_amdgcn_mfma_f32_16x16x32_bf16(kf0, qf[qt][0], s, 0, 0, 0);
          s = __builtin_amdgcn_mfma_f32_16x16x32_bf16(kf1, qf[qt][1], s, 0, 0, 0);
          fu32 e0, e1, e2, e3;
          e0.f = __builtin_amdgcn_exp2f(s[0]);
          e1.f = __builtin_amdgcn_exp2f(s[1]);
          e2.f = __builtin_amdgcn_exp2f(s[2]);
          e3.f = __builtin_amdgcn_exp2f(s[3]);
          pk[qt][t].x = __builtin_amdgcn_perm(e1.u, e0.u, 0x07060302u);
          pk[qt][t].y = __builtin_amdgcn_perm(e3.u, e2.u, 0x07060302u);
        }
      }
      // assemble A-layout P fragments (32 keys) in registers, then PV + l
      bf16x8 vf[4];
#pragma unroll
      for (int dt = 0; dt < 4; ++dt)
        vf[dt] = *(const bf16x8*)&vt_sh[(dt * 16 + l16) * 128 + ((ck * 4 + quad) ^ l16) * 8];
#pragma unroll
      for (int qt = 0; qt < 4; ++qt) {
        // pre-exchange pk[1] across quad^1 (lane^16)
        unsigned p1x = (unsigned)__shfl_xor((int)pk[qt][1].x, 16);
        unsigned p1y = (unsigned)__shfl_xor((int)pk[qt][1].y, 16);
        // per-dword contributions (source-lane side)
        unsigned v0x = qeven ? pk[qt][0].x : p1x;
        unsigned v0y = qeven ? pk[qt][0].y : p1y;
        unsigned v2x = qeven ? p1x : pk[qt][0].x;
        unsigned v2y = qeven ? p1y : pk[qt][0].y;
        pfu pf;
        pf.u.x = (unsigned)__builtin_amdgcn_ds_bpermute(addrA, (int)v0x);
        pf.u.y = (unsigned)__builtin_amdgcn_ds_bpermute(addrA, (int)v0y);
        pf.u.z = (unsigned)__builtin_amdgcn_ds_bpermute(addrB, (int)v2x);
        pf.u.w = (unsigned)__builtin_amdgcn_ds_bpermute(addrB, (int)v2y);
        l_acc[qt] = __builtin_amdgcn_mfma_f32_16x16x32_bf16(pf.v, ones, l_acc[qt], 0, 0, 0);
#pragma unroll
        for (int dt = 0; dt < 4; ++dt)
          o_acc[qt][dt] = __builtin_amdgcn_mfma_f32_16x16x32_bf16(pf.v, vf[dt], o_acc[qt][dt], 0, 0, 0);
      }
    }
  }

  // epilogue: l_acc is in the same C-layout as o_acc (row = query quad*4+r,
  // value replicated across l16) -> zero-shuffle normalization.
  short* Op = half ? Op1 : Op0;
#pragma unroll
  for (int qt = 0; qt < 4; ++qt) {
#pragma unroll
    for (int r = 0; r < 4; ++r) {
      const int qg = q0 + w * 64 + qt * 16 + quad * 4 + r;
      const size_t row = (size_t)(b * HH + h) * SS + qg;
      if (l16 == 0)
        lpw[(size_t)half * (NB * HH * SS) + row] = l_acc[qt][r];
      const float inv = __builtin_amdgcn_rcpf(l_acc[qt][r]);
#pragma unroll
      for (int dt = 0; dt < 4; ++dt)
        Op[row * DHH + dt * 16 + l16] = f2bf(o_acc[qt][dt][r] * inv);
    }
  }
}

// ------------------------ output projection + half-merge: 64x64 tile
// k-chunk of 64 == one head -> the A-tile is a contiguous 64x64 block of
// Op0/Op1.  Stage both halves, blend af = w1*o1n + w2*o2n during fragment
// construction (w from lpw, L2-resident).  grid (8,128) -> 4 blocks/CU.
__global__ __launch_bounds__(256, 4) void gemm_proj_kernel(
    const short* __restrict__ Op0, const short* __restrict__ Op1,
    const float* __restrict__ lpw, const short* __restrict__ Bt,
    const float* __restrict__ bias, float* __restrict__ out) {
  __shared__ __align__(16) short a0_sh[64 * 64];
  __shared__ __align__(16) short a1_sh[64 * 64];
  __shared__ __align__(16) short b_sh[64 * 64];
  const int tid = threadIdx.x;
  const int w   = tid >> 6, lane = tid & 63, quad = lane >> 4, l16 = lane & 15;
  const int m0  = blockIdx.y * 64, n0 = blockIdx.x * 64;
  const int mw  = (w >> 1) * 32, nw = (w & 1) * 32;
  const int rw  = lane >> 3, seg = lane & 7, gs = seg ^ rw;
  const int sxz = l16 & 7;
  const int bb  = m0 >> 11, q0 = m0 & (SS - 1);   // 64-row tile never crosses b

  f32x4 acc[2][2];
#pragma unroll
  for (int i = 0; i < 2; ++i)
#pragma unroll
    for (int j = 0; j < 2; ++j) acc[i][j] = {0.f, 0.f, 0.f, 0.f};

  for (int kt = 0; kt < DD; kt += 64) {
    const int h = kt >> 6;
    const size_t lbase = (size_t)(bb * HH + h) * SS + q0;
    const size_t abase = lbase * DHH;
    __syncthreads();
    {
      const short* g0 = Op0 + abase + (size_t)(w * 16 + rw) * DHH + gs * 8;
      const short* g1 = Op1 + abase + (size_t)(w * 16 + rw) * DHH + gs * 8;
      const short* gb = Bt + (size_t)(n0 + w * 16 + rw) * DD + kt + gs * 8;
#pragma unroll
      for (int i = 0; i < 2; ++i) {
        async16(g0 + (size_t)i * 8 * DHH, &a0_sh[(w * 16 + i * 8) * 64]);
        async16(g1 + (size_t)i * 8 * DHH, &a1_sh[(w * 16 + i * 8) * 64]);
        async16(gb + (size_t)i * 8 * DD,  &b_sh[(w * 16 + i * 8) * 64]);
      }
    }
    // merge weights per m-row while staging is in flight (lane l16 = m-row)
    float w1[2], w2[2];
#pragma unroll
    for (int mt = 0; mt < 2; ++mt) {
      const size_t lrow = lbase + mw + mt * 16 + l16;
      const float l1 = lpw[lrow];
      const float l2 = lpw[(size_t)NB * HH * SS + lrow];
      const float inv = __builtin_amdgcn_rcpf(l1 + l2);
      w1[mt] = l1 * inv; w2[mt] = l2 * inv;
    }
    __syncthreads();
#pragma unroll
    for (int ks = 0; ks < 2; ++ks) {
      const int so = ((ks * 4 + quad) ^ sxz) * 8;
      pfu af[2];
#pragma unroll
      for (int mt = 0; mt < 2; ++mt) {
        bf16x8 a0 = *(const bf16x8*)&a0_sh[(mw + mt * 16 + l16) * 64 + so];
        bf16x8 a1 = *(const bf16x8*)&a1_sh[(mw + mt * 16 + l16) * 64 + so];
        unsigned* rp = (unsigned*)&af[mt];
#pragma unroll
        for (int jp = 0; jp < 4; ++jp) {
          fu32 f0, f1;
          f0.f = w1[mt] * bf2f(a0[2 * jp])     + w2[mt] * bf2f(a1[2 * jp]);
          f1.f = w1[mt] * bf2f(a0[2 * jp + 1]) + w2[mt] * bf2f(a1[2 * jp + 1]);
          rp[jp] = __builtin_amdgcn_perm(f1.u, f0.u, 0x07060302u);  // trunc pack
        }
      }
#pragma unroll
      for (int nt = 0; nt < 2; ++nt) {
        bf16x8 bfr = *(const bf16x8*)&b_sh[(nw + nt * 16 + l16) * 64 + so];
        acc[0][nt] = __builtin_amdgcn_mfma_f32_16x16x32_bf16(af[0].v, bfr, acc[0][nt], 0, 0, 0);
        acc[1][nt] = __builtin_amdgcn_mfma_f32_16x16x32_bf16(af[1].v, bfr, acc[1][nt], 0, 0, 0);
      }
    }
  }

#pragma unroll
  for (int nt = 0; nt < 2; ++nt) {
    const int   n  = n0 + nw + nt * 16 + l16;
    const float bv = bias[n];
#pragma unroll
    for (int mt = 0; mt < 2; ++mt)
#pragma unroll
      for (int r = 0; r < 4; ++r) {
        const int m = m0 + mw + mt * 16 + quad * 4 + r;
        out[(size_t)m * DD + n] = acc[mt][nt][r] + bv;
      }
  }
}

// ---------------------------------------------------------------- launcher
extern "C" void kernel_launch(void* const* d_in, const int* in_sizes, int n_in,
                              void* d_out, int out_size, void* d_ws, size_t ws_size,
                              hipStream_t stream) {
  (void)in_sizes; (void)n_in; (void)out_size; (void)ws_size;
  const float* x  = (const float*)d_in[0];
  const float* Wq = (const float*)d_in[1];
  const float* bq = (const float*)d_in[2];
  const float* Wk = (const float*)d_in[3];
  const float* bk = (const float*)d_in[4];
  const float* Wv = (const float*)d_in[5];
  const float* bv = (const float*)d_in[6];
  const float* Wh = (const float*)d_in[7];
  const float* bh = (const float*)d_in[8];

  short* ws  = (short*)d_ws;
  short* xb  = ws;                              // x bf16 [8192,512]; reused as Op0
  short* wqt = xb  + (size_t)MM * DD;           // Wq^T bf16 [512,512]
  short* wkt = wqt + (size_t)DD * DD;           // (wqt..wvt contiguous = QKV Bt)
  short* wvt = wkt + (size_t)DD * DD;
  short* wht = wvt + (size_t)DD * DD;
  short* qws = wht + (size_t)DD * DD;           // q bf16 [B,H,S,64] (pre-scaled)
  short* kws = qws + (size_t)MM * DD;           // k bf16 [B,H,S,64]
  short* vws = kws + (size_t)MM * DD;           // v^T bf16 [B,H,64,S]
  short* op1 = vws + (size_t)MM * DD;           // partial O half1 [B,H,S,64]
  float* lpw = (float*)(op1 + (size_t)MM * DD); // partial l [2][B*H*S]

  hipLaunchKernelGGL(prep_kernel, dim3(2048 + 256), dim3(256), 0, stream,
                     x, xb, Wq, Wk, Wv, Wh, wqt, wkt, wvt, wht);

  // q pre-scale: (1/sqrt(64)) * log2(e) so softmax uses exp2 directly
  const float qscale = 1.4426950408889634f / 8.0f;
  hipLaunchKernelGGL(gemm_qkv_kernel, dim3(12, 128), dim3(256), 0, stream,
                     xb, wqt, bq, bk, bv, qws, kws, vws, qscale);

  // Op0 reuses xb (dead after gemm_qkv)
  hipLaunchKernelGGL(attn_kernel, dim3(512), dim3(256), 0, stream,
                     qws, kws, vws, xb, op1, lpw);

  // projection merges the two key-halves in its A-operand path
  hipLaunchKernelGGL(gemm_proj_kernel, dim3(8, 128), dim3(256), 0, stream,
                     xb, op1, lpw, wht, bh, (float*)d_out);
}

// Round 13
// 171.843 us; speedup vs baseline: 1.0305x; 1.0305x over previous
//
#include <hip/hip_runtime.h>
#include <stdint.h>

// Problem constants (reference: B=4, S=2048, D=512, H=8, d_head=64)
#define NB  4
#define SS  2048
#define DD  512
#define HH  8
#define DHH 64
#define MM  (NB * SS)   // 8192 rows

typedef __attribute__((ext_vector_type(8))) short bf16x8;  // 8 bf16 in 4 VGPRs
typedef __attribute__((ext_vector_type(4))) float f32x4;   // MFMA C/D frag
typedef __attribute__((ext_vector_type(4))) short s16x4;   // 8 B pack

union fu32 { float f; unsigned u; };
union pfu  { uint4 u; bf16x8 v; };

// fp32 -> bf16 round-to-nearest-even (bit pattern in a short)
static __device__ __forceinline__ short f2bf(float f) {
  fu32 a; a.f = f;
  unsigned u = a.u;
  return (short)((u + 0x7fffu + ((u >> 16) & 1u)) >> 16);
}
static __device__ __forceinline__ float bf2f(short s) {
  fu32 t; t.u = ((unsigned)(unsigned short)s) << 16;
  return t.f;
}

// async global->LDS, 16 B/lane; LDS dest = wave-uniform base + lane*16
static __device__ __forceinline__ void async16(const void* g, void* l) {
  __builtin_amdgcn_global_load_lds(
      (__attribute__((address_space(1))) unsigned*)(void*)g,
      (__attribute__((address_space(3))) unsigned*)l, 16, 0, 0);
}

// ------------------------------- prep: x->bf16 (blocks 0..2047) and
//                                 W[k][n] fp32 -> Wt[n][k] bf16 (2048..2303)
__global__ __launch_bounds__(256) void prep_kernel(
    const float* __restrict__ x, short* __restrict__ xb,
    const float* __restrict__ W0, const float* __restrict__ W1,
    const float* __restrict__ W2, const float* __restrict__ W3,
    short* __restrict__ T0, short* __restrict__ T1,
    short* __restrict__ T2, short* __restrict__ T3) {
  const int bid = blockIdx.x, tid = threadIdx.x;
  if (bid < 2048) {
    int i = (bid * 256 + tid) * 8;
    float4 v0 = *(const float4*)(x + i);
    float4 v1 = *(const float4*)(x + i + 4);
    bf16x8 o;
    o[0] = f2bf(v0.x); o[1] = f2bf(v0.y); o[2] = f2bf(v0.z); o[3] = f2bf(v0.w);
    o[4] = f2bf(v1.x); o[5] = f2bf(v1.y); o[6] = f2bf(v1.z); o[7] = f2bf(v1.w);
    *(bf16x8*)(xb + i) = o;
  } else {
    int z = bid - 2048;                 // 0..255
    int widx = z >> 6, rem = z & 63;
    const float* W = widx == 0 ? W0 : widx == 1 ? W1 : widx == 2 ? W2 : W3;
    short*       T = widx == 0 ? T0 : widx == 1 ? T1 : widx == 2 ? T2 : T3;
    int n  = (rem & 7) * 64 + (tid & 63);
    int k0 = (rem >> 3) * 64 + (tid >> 6) * 16;
    bf16x8 t0, t1;
#pragma unroll
    for (int j = 0; j < 8; ++j) t0[j] = f2bf(W[(size_t)(k0 + j) * DD + n]);
#pragma unroll
    for (int j = 0; j < 8; ++j) t1[j] = f2bf(W[(size_t)(k0 + 8 + j) * DD + n]);
    *(bf16x8*)(T + (size_t)n * DD + k0)     = t0;
    *(bf16x8*)(T + (size_t)n * DD + k0 + 8) = t1;
  }
}

// ---------------------------------------- fused QKV GEMM: 64x128, N = 1536
// grid (12,128) = 1536 blocks -> 4 blocks/CU.  global_load_lds staging,
// XOR-swizzled segments.  Epilogue goes through an LDS transpose tile so all
// global stores are coalesced b128 (no sector amplification): q,k [B,H,S,64]
// (q pre-scaled), v [B,H,64,S].
__global__ __launch_bounds__(256, 4) void gemm_qkv_kernel(
    const short* __restrict__ A, const short* __restrict__ Bt,
    const float* __restrict__ bq, const float* __restrict__ bk,
    const float* __restrict__ bv, short* __restrict__ qout,
    short* __restrict__ kout, short* __restrict__ vtout, float qscale) {
  __shared__ __align__(16) short sh[64 * 64 + 128 * 64];   // 24 KB flat
  short* a_sh = sh;                 // [64 x 64]
  short* b_sh = sh + 64 * 64;       // [128 x 64]
  const int tid  = threadIdx.x;
  const int w    = tid >> 6, lane = tid & 63, quad = lane >> 4, l16 = lane & 15;
  const int m0   = blockIdx.y * 64, n0 = blockIdx.x * 128;
  const int mw   = (w >> 1) * 32,   nw = (w & 1) * 64;
  const int rw   = lane >> 3, seg = lane & 7, gs = seg ^ rw;  // row&7 == rw
  const int sxz  = l16 & 7;   // fragment-read swizzle key

  f32x4 acc[2][4];
#pragma unroll
  for (int i = 0; i < 2; ++i)
#pragma unroll
    for (int j = 0; j < 4; ++j) acc[i][j] = {0.f, 0.f, 0.f, 0.f};

  for (int kt = 0; kt < DD; kt += 64) {
    __syncthreads();
    {
      const short* ga = A  + (size_t)(m0 + w * 16 + rw) * DD + kt + gs * 8;
      const short* gb = Bt + (size_t)(n0 + w * 32 + rw) * DD + kt + gs * 8;
#pragma unroll
      for (int i = 0; i < 2; ++i)
        async16(ga + (size_t)i * 8 * DD, &a_sh[(w * 16 + i * 8) * 64]);
#pragma unroll
      for (int i = 0; i < 4; ++i)
        async16(gb + (size_t)i * 8 * DD, &b_sh[(w * 32 + i * 8) * 64]);
    }
    __syncthreads();
#pragma unroll
    for (int ks = 0; ks < 2; ++ks) {
      const int so = ((ks * 4 + quad) ^ sxz) * 8;
      bf16x8 af[2], bfr[4];
#pragma unroll
      for (int mt = 0; mt < 2; ++mt)
        af[mt] = *(const bf16x8*)&a_sh[(mw + mt * 16 + l16) * 64 + so];
#pragma unroll
      for (int nt = 0; nt < 4; ++nt)
        bfr[nt] = *(const bf16x8*)&b_sh[(nw + nt * 16 + l16) * 64 + so];
#pragma unroll
      for (int mt = 0; mt < 2; ++mt)
#pragma unroll
        for (int nt = 0; nt < 4; ++nt)
          acc[mt][nt] = __builtin_amdgcn_mfma_f32_16x16x32_bf16(
              af[mt], bfr[nt], acc[mt][nt], 0, 0, 0);
    }
  }

  // -------- epilogue via LDS transpose tile (sg uniform per block) --------
  __syncthreads();                       // main-loop reads of sh done
  const int sgb = n0 >> 9;               // 0=q 1=k 2=v
  const int h0  = (n0 & 511) >> 6;       // first head in this block
  const int bi  = m0 >> 11, s0 = m0 & (SS - 1);
  if (sgb < 2) {
    const float* bias = (sgb == 0) ? bq : bk;
    const float  scl  = (sgb == 0) ? qscale : 1.0f;
    // tile [s][d] 64 x 128, pad 136
#pragma unroll
    for (int nt = 0; nt < 4; ++nt) {
      const int dl = nw + nt * 16 + l16;                  // 0..127
      const float bval = bias[(n0 & 511) + dl];
#pragma unroll
      for (int mt = 0; mt < 2; ++mt)
#pragma unroll
        for (int r = 0; r < 4; ++r)
          sh[(mw + mt * 16 + quad * 4 + r) * 136 + dl] =
              f2bf((acc[mt][nt][r] + bval) * scl);
    }
    __syncthreads();
    short* o = (sgb == 0) ? qout : kout;
#pragma unroll
    for (int i = 0; i < 4; ++i) {
      const int c = tid + 256 * i;                        // 0..1023
      const int s = c >> 4, d8 = (c & 15) * 8;
      const int hh = h0 + (d8 >> 6), dd = d8 & 63;
      *(bf16x8*)&o[((size_t)(bi * HH + hh) * SS + s0 + s) * DHH + dd] =
          *(const bf16x8*)&sh[s * 136 + d8];
    }
  } else {
    // tile [d][s] 128 x 64, pad 72
#pragma unroll
    for (int nt = 0; nt < 4; ++nt) {
      const int dl = nw + nt * 16 + l16;
      const float bval = bv[(n0 & 511) + dl];
#pragma unroll
      for (int mt = 0; mt < 2; ++mt)
#pragma unroll
        for (int r = 0; r < 4; ++r)
          sh[dl * 72 + mw + mt * 16 + quad * 4 + r] = f2bf(acc[mt][nt][r] + bval);
    }
    __syncthreads();
#pragma unroll
    for (int i = 0; i < 4; ++i) {
      const int c = tid + 256 * i;
      const int d = c >> 3, s8 = (c & 7) * 8;
      const int hh = h0 + (d >> 6), dd = d & 63;
      *(bf16x8*)&vtout[((size_t)(bi * HH + hh) * DHH + dd) * SS + s0 + s8] =
          *(const bf16x8*)&sh[d * 72 + s8];
    }
  }
}

// ----------------------------------------------- flash attention, key-split
// qt=4 register blocking (64 q/wave), 256-key staging (4 barrier pairs
// instead of 8).  S^T = K·Q^T; P fragments assembled in registers (pack ->
// ^16 exchange -> select -> 4 ds_bpermute); softmax denominator via
// MFMA-vs-ones; zero-shuffle normalization.
__global__ __launch_bounds__(256, 2) void attn_kernel(
    const short* __restrict__ Qa, const short* __restrict__ Ka,
    const short* __restrict__ Vt, short* __restrict__ Op0,
    short* __restrict__ Op1, float* __restrict__ lpw) {
  __shared__ __align__(16) short k_sh[256 * 64];     // 32 KB, swizzled segs
  __shared__ __align__(16) short vt_sh[64 * 256];    // 32 KB, swizzled segs

  const int tid  = threadIdx.x;
  const int w    = tid >> 6, lane = tid & 63, quad = lane >> 4, l16 = lane & 15;
  // XCD-aware decode: xcd = n&7; 8 (b,h,half) groups x 8 q-tiles per XCD
  const int n    = blockIdx.x;                 // 0..511
  const int grp  = (n & 7) * 8 + ((n >> 3) & 7);   // (b,h,half) group, 0..63
  const int qt_b = n >> 6;                     // 0..7 (256-query tiles)
  const int half = grp & 1, h = (grp >> 1) & 7, b = grp >> 4;
  const int q0   = qt_b * 256;
  const int rw = lane >> 3, seg = lane & 7, gs = seg ^ rw;
  const int sxz = l16 & 7;
  const size_t base = (size_t)(b * HH + h) * SS * DHH;
  const short* Qg = Qa + base + (size_t)(q0 + w * 64) * DHH;
  const short* Kg = Ka + base;
  const short* Vg = Vt + base;           // [64][S]

  // Q fragments (usable as A or B operand: same lane map)
  bf16x8 qf[4][2];
#pragma unroll
  for (int qt = 0; qt < 4; ++qt)
#pragma unroll
    for (int ks = 0; ks < 2; ++ks)
      qf[qt][ks] = *(const bf16x8*)(Qg + (size_t)(qt * 16 + l16) * DHH + ks * 32 + quad * 8);

  bf16x8 ones;
#pragma unroll
  for (int j = 0; j < 8; ++j) ones[j] = (short)0x3F80;   // bf16 1.0

  f32x4 o_acc[4][4];
#pragma unroll
  for (int qt = 0; qt < 4; ++qt)
#pragma unroll
    for (int dt = 0; dt < 4; ++dt) o_acc[qt][dt] = {0.f, 0.f, 0.f, 0.f};
  f32x4 l_acc[4];
#pragma unroll
  for (int qt = 0; qt < 4; ++qt) l_acc[qt] = {0.f, 0.f, 0.f, 0.f};

  // bpermute byte-addresses for the verified cross-quad gather:
  // dwords 0/1 pull from src_quad = (quad&1)*2 + (quad>>1); dwords 2/3 from ^1
  const int addrA = ((((quad & 1) << 1) + (quad >> 1)) * 16 + l16) * 4;
  const int addrB = addrA ^ 64;
  const bool qeven = (quad & 1) == 0;

  const int kstart = half * (SS / 2);

  for (int kb = kstart; kb < kstart + SS / 2; kb += 256) {
    __syncthreads();   // WAR on k_sh / vt_sh
    {
      // K: 256 rows x 64 d; wave stages 64 rows (8 calls x 8 rows)
      const short* gk = Kg + (size_t)(kb + w * 64 + rw) * DHH + gs * 8;
#pragma unroll
      for (int i = 0; i < 8; ++i)
        async16(gk + (size_t)i * 8 * DHH, &k_sh[(w * 64 + i * 8) * 64]);
      // V^T: 64 d-rows x 256 keys; wave stages 16 rows (8 calls x 2 rows)
#pragma unroll
      for (int i = 0; i < 8; ++i) {
        const int d = w * 16 + i * 2 + (lane >> 5);
        const int kseg = (lane & 31) ^ (d & 31);
        async16(Vg + (size_t)d * SS + kb + kseg * 8,
                &vt_sh[(w * 16 + i * 2) * 256]);
      }
    }
    __syncthreads();

    // 8 chunks of 32 keys: QK^T (2 tiles) -> exp2/pack -> permute -> PV + l
#pragma unroll
    for (int ck = 0; ck < 8; ++ck) {
      uint2 pk[4][2];   // [qt][tile]
#pragma unroll
      for (int t = 0; t < 2; ++t) {
        const int knt = ck * 2 + t;
        bf16x8 kf0 = *(const bf16x8*)&k_sh[(knt * 16 + l16) * 64 + ((0 * 4 + quad) ^ sxz) * 8];
        bf16x8 kf1 = *(const bf16x8*)&k_sh[(knt * 16 + l16) * 64 + ((1 * 4 + quad) ^ sxz) * 8];
#pragma unroll
        for (int qt = 0; qt < 4; ++qt) {
          f32x4 s = {0.f, 0.f, 0.f, 0.f};
          s = __builtin_amdgcn_mfma_f32_16x16x32_bf16(kf0, qf[qt][0], s, 0, 0, 0);
          s = __builtin_amdgcn_mfma_f32_16x16x32_bf16(kf1, qf[qt][1], s, 0, 0, 0);
          fu32 e0, e1, e2, e3;
          e0.f = __builtin_amdgcn_exp2f(s[0]);
          e1.f = __builtin_amdgcn_exp2f(s[1]);
          e2.f = __builtin_amdgcn_exp2f(s[2]);
          e3.f = __builtin_amdgcn_exp2f(s[3]);
          pk[qt][t].x = __builtin_amdgcn_perm(e1.u, e0.u, 0x07060302u);
          pk[qt][t].y = __builtin_amdgcn_perm(e3.u, e2.u, 0x07060302u);
        }
      }
      // assemble A-layout P fragments (32 keys) in registers, then PV + l
      bf16x8 vf[4];
#pragma unroll
      for (int dt = 0; dt < 4; ++dt) {
        const int dl = dt * 16 + l16;
        vf[dt] = *(const bf16x8*)&vt_sh[dl * 256 + ((ck * 4 + quad) ^ (dl & 31)) * 8];
      }
#pragma unroll
      for (int qt = 0; qt < 4; ++qt) {
        // pre-exchange pk[1] across quad^1 (lane^16)
        unsigned p1x = (unsigned)__shfl_xor((int)pk[qt][1].x, 16);
        unsigned p1y = (unsigned)__shfl_xor((int)pk[qt][1].y, 16);
        // per-dword contributions (source-lane side)
        unsigned v0x = qeven ? pk[qt][0].x : p1x;
        unsigned v0y = qeven ? pk[qt][0].y : p1y;
        unsigned v2x = qeven ? p1x : pk[qt][0].x;
        unsigned v2y = qeven ? p1y : pk[qt][0].y;
        pfu pf;
        pf.u.x = (unsigned)__builtin_amdgcn_ds_bpermute(addrA, (int)v0x);
        pf.u.y = (unsigned)__builtin_amdgcn_ds_bpermute(addrA, (int)v0y);
        pf.u.z = (unsigned)__builtin_amdgcn_ds_bpermute(addrB, (int)v2x);
        pf.u.w = (unsigned)__builtin_amdgcn_ds_bpermute(addrB, (int)v2y);
        l_acc[qt] = __builtin_amdgcn_mfma_f32_16x16x32_bf16(pf.v, ones, l_acc[qt], 0, 0, 0);
#pragma unroll
        for (int dt = 0; dt < 4; ++dt)
          o_acc[qt][dt] = __builtin_amdgcn_mfma_f32_16x16x32_bf16(pf.v, vf[dt], o_acc[qt][dt], 0, 0, 0);
      }
    }
  }

  // epilogue: l_acc is in the same C-layout as o_acc (row = query quad*4+r,
  // value replicated across l16) -> zero-shuffle normalization.
  short* Op = half ? Op1 : Op0;
#pragma unroll
  for (int qt = 0; qt < 4; ++qt) {
#pragma unroll
    for (int r = 0; r < 4; ++r) {
      const int qg = q0 + w * 64 + qt * 16 + quad * 4 + r;
      const size_t row = (size_t)(b * HH + h) * SS + qg;
      if (l16 == 0)
        lpw[(size_t)half * (NB * HH * SS) + row] = l_acc[qt][r];
      const float inv = __builtin_amdgcn_rcpf(l_acc[qt][r]);
#pragma unroll
      for (int dt = 0; dt < 4; ++dt)
        Op[row * DHH + dt * 16 + l16] = f2bf(o_acc[qt][dt][r] * inv);
    }
  }
}

// ------------------------ output projection + half-merge: 64x64 tile
// k-chunk of 64 == one head -> the A-tile is a contiguous 64x64 block of
// Op0/Op1.  Stage both halves, blend af = w1*o1n + w2*o2n during fragment
// construction (w from lpw, L2-resident).  grid (8,128) -> 4 blocks/CU.
__global__ __launch_bounds__(256, 4) void gemm_proj_kernel(
    const short* __restrict__ Op0, const short* __restrict__ Op1,
    const float* __restrict__ lpw, const short* __restrict__ Bt,
    const float* __restrict__ bias, float* __restrict__ out) {
  __shared__ __align__(16) short a0_sh[64 * 64];
  __shared__ __align__(16) short a1_sh[64 * 64];
  __shared__ __align__(16) short b_sh[64 * 64];
  const int tid = threadIdx.x;
  const int w   = tid >> 6, lane = tid & 63, quad = lane >> 4, l16 = lane & 15;
  const int m0  = blockIdx.y * 64, n0 = blockIdx.x * 64;
  const int mw  = (w >> 1) * 32, nw = (w & 1) * 32;
  const int rw  = lane >> 3, seg = lane & 7, gs = seg ^ rw;
  const int sxz = l16 & 7;
  const int bb  = m0 >> 11, q0 = m0 & (SS - 1);   // 64-row tile never crosses b

  f32x4 acc[2][2];
#pragma unroll
  for (int i = 0; i < 2; ++i)
#pragma unroll
    for (int j = 0; j < 2; ++j) acc[i][j] = {0.f, 0.f, 0.f, 0.f};

  for (int kt = 0; kt < DD; kt += 64) {
    const int h = kt >> 6;
    const size_t lbase = (size_t)(bb * HH + h) * SS + q0;
    const size_t abase = lbase * DHH;
    __syncthreads();
    {
      const short* g0 = Op0 + abase + (size_t)(w * 16 + rw) * DHH + gs * 8;
      const short* g1 = Op1 + abase + (size_t)(w * 16 + rw) * DHH + gs * 8;
      const short* gb = Bt + (size_t)(n0 + w * 16 + rw) * DD + kt + gs * 8;
#pragma unroll
      for (int i = 0; i < 2; ++i) {
        async16(g0 + (size_t)i * 8 * DHH, &a0_sh[(w * 16 + i * 8) * 64]);
        async16(g1 + (size_t)i * 8 * DHH, &a1_sh[(w * 16 + i * 8) * 64]);
        async16(gb + (size_t)i * 8 * DD,  &b_sh[(w * 16 + i * 8) * 64]);
      }
    }
    // merge weights per m-row while staging is in flight (lane l16 = m-row)
    float w1[2], w2[2];
#pragma unroll
    for (int mt = 0; mt < 2; ++mt) {
      const size_t lrow = lbase + mw + mt * 16 + l16;
      const float l1 = lpw[lrow];
      const float l2 = lpw[(size_t)NB * HH * SS + lrow];
      const float inv = __builtin_amdgcn_rcpf(l1 + l2);
      w1[mt] = l1 * inv; w2[mt] = l2 * inv;
    }
    __syncthreads();
#pragma unroll
    for (int ks = 0; ks < 2; ++ks) {
      const int so = ((ks * 4 + quad) ^ sxz) * 8;
      pfu af[2];
#pragma unroll
      for (int mt = 0; mt < 2; ++mt) {
        bf16x8 a0 = *(const bf16x8*)&a0_sh[(mw + mt * 16 + l16) * 64 + so];
        bf16x8 a1 = *(const bf16x8*)&a1_sh[(mw + mt * 16 + l16) * 64 + so];
        unsigned* rp = (unsigned*)&af[mt];
#pragma unroll
        for (int jp = 0; jp < 4; ++jp) {
          fu32 f0, f1;
          f0.f = w1[mt] * bf2f(a0[2 * jp])     + w2[mt] * bf2f(a1[2 * jp]);
          f1.f = w1[mt] * bf2f(a0[2 * jp + 1]) + w2[mt] * bf2f(a1[2 * jp + 1]);
          rp[jp] = __builtin_amdgcn_perm(f1.u, f0.u, 0x07060302u);  // trunc pack
        }
      }
#pragma unroll
      for (int nt = 0; nt < 2; ++nt) {
        bf16x8 bfr = *(const bf16x8*)&b_sh[(nw + nt * 16 + l16) * 64 + so];
        acc[0][nt] = __builtin_amdgcn_mfma_f32_16x16x32_bf16(af[0].v, bfr, acc[0][nt], 0, 0, 0);
        acc[1][nt] = __builtin_amdgcn_mfma_f32_16x16x32_bf16(af[1].v, bfr, acc[1][nt], 0, 0, 0);
      }
    }
  }

#pragma unroll
  for (int nt = 0; nt < 2; ++nt) {
    const int   n  = n0 + nw + nt * 16 + l16;
    const float bv = bias[n];
#pragma unroll
    for (int mt = 0; mt < 2; ++mt)
#pragma unroll
      for (int r = 0; r < 4; ++r) {
        const int m = m0 + mw + mt * 16 + quad * 4 + r;
        out[(size_t)m * DD + n] = acc[mt][nt][r] + bv;
      }
  }
}

// ---------------------------------------------------------------- launcher
extern "C" void kernel_launch(void* const* d_in, const int* in_sizes, int n_in,
                              void* d_out, int out_size, void* d_ws, size_t ws_size,
                              hipStream_t stream) {
  (void)in_sizes; (void)n_in; (void)out_size; (void)ws_size;
  const float* x  = (const float*)d_in[0];
  const float* Wq = (const float*)d_in[1];
  const float* bq = (const float*)d_in[2];
  const float* Wk = (const float*)d_in[3];
  const float* bk = (const float*)d_in[4];
  const float* Wv = (const float*)d_in[5];
  const float* bv = (const float*)d_in[6];
  const float* Wh = (const float*)d_in[7];
  const float* bh = (const float*)d_in[8];

  short* ws  = (short*)d_ws;
  short* xb  = ws;                              // x bf16 [8192,512]; reused as Op0
  short* wqt = xb  + (size_t)MM * DD;           // Wq^T bf16 [512,512]
  short* wkt = wqt + (size_t)DD * DD;           // (wqt..wvt contiguous = QKV Bt)
  short* wvt = wkt + (size_t)DD * DD;
  short* wht = wvt + (size_t)DD * DD;
  short* qws = wht + (size_t)DD * DD;           // q bf16 [B,H,S,64] (pre-scaled)
  short* kws = qws + (size_t)MM * DD;           // k bf16 [B,H,S,64]
  short* vws = kws + (size_t)MM * DD;           // v^T bf16 [B,H,64,S]
  short* op1 = vws + (size_t)MM * DD;           // partial O half1 [B,H,S,64]
  float* lpw = (float*)(op1 + (size_t)MM * DD); // partial l [2][B*H*S]

  hipLaunchKernelGGL(prep_kernel, dim3(2048 + 256), dim3(256), 0, stream,
                     x, xb, Wq, Wk, Wv, Wh, wqt, wkt, wvt, wht);

  // q pre-scale: (1/sqrt(64)) * log2(e) so softmax uses exp2 directly
  const float qscale = 1.4426950408889634f / 8.0f;
  hipLaunchKernelGGL(gemm_qkv_kernel, dim3(12, 128), dim3(256), 0, stream,
                     xb, wqt, bq, bk, bv, qws, kws, vws, qscale);

  // Op0 reuses xb (dead after gemm_qkv)
  hipLaunchKernelGGL(attn_kernel, dim3(512), dim3(256), 0, stream,
                     qws, kws, vws, xb, op1, lpw);

  // projection merges the two key-halves in its A-operand path
  hipLaunchKernelGGL(gemm_proj_kernel, dim3(8, 128), dim3(256), 0, stream,
                     xb, op1, lpw, wht, bh, (float*)d_out);
}